// Round 4
// baseline (417.025 us; speedup 1.0000x reference)
//
#include <hip/hip_runtime.h>
#include <stdint.h>

#define NB 8
#define NL 2048
#define ND 256
#define KVB 32
#define NT_ALL (NL / KVB)

typedef __attribute__((ext_vector_type(8))) short short8;
typedef __attribute__((ext_vector_type(4))) short short4v;
typedef __attribute__((ext_vector_type(4))) float f32x4;

__device__ __forceinline__ unsigned short bf16rne(float x) {
  unsigned u = __builtin_bit_cast(unsigned, x);
  u += 0x7FFFu + ((u >> 16) & 1u);
  return (unsigned short)(u >> 16);
}

__device__ __forceinline__ short8 cvt8(float4 a, float4 b, float scale) {
  short8 v;
  v[0] = (short)bf16rne(a.x * scale);
  v[1] = (short)bf16rne(a.y * scale);
  v[2] = (short)bf16rne(a.z * scale);
  v[3] = (short)bf16rne(a.w * scale);
  v[4] = (short)bf16rne(b.x * scale);
  v[5] = (short)bf16rne(b.y * scale);
  v[6] = (short)bf16rne(b.z * scale);
  v[7] = (short)bf16rne(b.w * scale);
  return v;
}

// Pre-pass: detect mask storage. If any of the first 4096 words is not 0/1,
// the mask is byte-packed (numpy bool) -> flag=1; else int32 words -> flag=0.
__global__ void mask_mode_kernel(const unsigned* __restrict__ M, int* __restrict__ flag) {
  bool bad = false;
  for (int i = threadIdx.x; i < 4096; i += 64) {
    unsigned w = M[i];
    if (w > 1u) bad = true;
  }
  unsigned long long b = __ballot(bad);
  if (threadIdx.x == 0) *flag = (b != 0ULL) ? 1 : 0;
}

// Flash attention fwd: 2 waves/block, 32 q-rows/block (16 per wave),
// KVB=32 K/V tiles staged fp32->bf16 in LDS. Causal + padding applied as
// -1e4 additive biases EXACTLY like the reference (finite, tie with each
// other; rows whose whole causal prefix is padding-masked keep reading
// kv>q tiles -> "needy" extension).
__global__ __launch_bounds__(128, 2)
void attn_fwd(const float* __restrict__ Qg, const float* __restrict__ Kg,
              const float* __restrict__ Vg, const int* __restrict__ Mg,
              float* __restrict__ Og, const int* __restrict__ modeFlag) {
  __shared__ unsigned short Ks[KVB * ND];      // 16 KB, row-major + XOR swizzle
  __shared__ unsigned short Vs[KVB * ND];      // 16 KB, subtiled [kv/4][f/16][4][16]
  __shared__ float biasS[KVB];                 // padding-mask bias per kv row
  __shared__ unsigned short Ps[2][16 * KVB];   // per-wave P (bf16)
  __shared__ int contS;                        // needy-extension flag

  const int tid = threadIdx.x;
  const int wv = tid >> 6;       // wave 0/1
  const int lane = tid & 63;
  const int g = lane >> 4;       // 4-lane-group id (0..3)
  const int cc = lane & 15;      // column/lane-in-group (0..15)

  const int maskByteMode = modeFlag ? *modeFlag : 0;

  // balanced grid mapping: pairs (qt, 63-qt) -> constant causal work
  const int bid = blockIdx.x;    // 0..511
  const int half = bid >> 8;
  const int ci = bid & 255;
  const int b = ci >> 5;         // batch 0..7
  const int jj = ci & 31;
  const int qt = half ? (63 - jj) : jj;  // q-tile 0..63 (32 rows each)
  const int qb = qt * 32;

  // ---- Q fragments: lane holds Q[qrow = cc][ch*32 + g*8 .. +7], scaled 1/16
  const float* qp = Qg + ((size_t)b * NL + (qb + 16 * wv + cc)) * ND;
  short8 qf[8];
#pragma unroll
  for (int ch = 0; ch < 8; ++ch) {
    int f = ch * 32 + g * 8;
    float4 a0 = *reinterpret_cast<const float4*>(qp + f);
    float4 a1 = *reinterpret_cast<const float4*>(qp + f + 4);
    qf[ch] = cvt8(a0, a1, 0.0625f);
  }

  f32x4 acc[16];
#pragma unroll
  for (int i = 0; i < 16; ++i) acc[i] = (f32x4){0.f, 0.f, 0.f, 0.f};
  float m_run[4], l_run[4];
#pragma unroll
  for (int r = 0; r < 4; ++r) { m_run[r] = -3.0e38f; l_run[r] = 0.f; }

  // tr-read: 16-lane-group gather; NATURAL addressing = base + 8 bytes/lane.
  // Group g reads subtile [kvBlk=2g(+1)][fBlk=ft] of the [8][16][4][16] V
  // layout; result elem j = subtile row j, col cc = V[kv=8g(+4)+j][ft*16+cc].
  const unsigned vsb = (unsigned)(uintptr_t)(&Vs[0]);
  const unsigned va = vsb + g * 4096 + cc * 8;   // <-- 8 B/lane (was the bug)
  const int nt = qt + 1;                         // causal tiles: 0..qt

  for (int tix = 0; tix < NT_ALL; ++tix) {
    if (tix == nt) {
      // continue past the causal prefix only if some row is still stuck in
      // the -10000 tier (whole prefix padding-masked): reference semantics
      // make the causally-masked tail (same tier) compete for mass.
      bool needy = (m_run[0] < -5000.f) || (m_run[1] < -5000.f) ||
                   (m_run[2] < -5000.f) || (m_run[3] < -5000.f);
      unsigned long long bal = __ballot(needy);
      if (tid == 0) contS = 0;
      __syncthreads();
      if (lane == 0 && bal != 0ULL) contS = 1;
      __syncthreads();
      if (contS == 0) break;
    }
    const int kv0 = tix * KVB;
    __syncthreads();
    // ---- stage K,V (fp32 -> bf16) + padding bias
    {
      const float* kt = Kg + ((size_t)b * NL + kv0) * ND;
      const float* vt = Vg + ((size_t)b * NL + kv0) * ND;
#pragma unroll
      for (int it = 0; it < 8; ++it) {
        int idx = it * 128 + tid;   // unit = 8 floats; 32 rows x 32 units
        int row = idx >> 5;
        int u = idx & 31;
        int f = u * 8;
        const float4* kp4 = reinterpret_cast<const float4*>(kt + (size_t)row * ND + f);
        float4 k0 = kp4[0], k1 = kp4[1];
        int kb = (row * 512 + f * 2) ^ ((row & 7) << 4);
        *reinterpret_cast<short8*>((char*)Ks + kb) = cvt8(k0, k1, 1.0f);
        const float4* vp4 = reinterpret_cast<const float4*>(vt + (size_t)row * ND + f);
        float4 v0 = vp4[0], v1 = vp4[1];
        int vb = (row >> 2) * 2048 + (u >> 1) * 128 + (row & 3) * 32 + (u & 1) * 16;
        *reinterpret_cast<short8*>((char*)Vs + vb) = cvt8(v0, v1, 1.0f);
      }
      if (tid < KVB) {
        int mv = maskByteMode
                     ? (int)((const unsigned char*)Mg)[(size_t)b * NL + kv0 + tid]
                     : Mg[(size_t)b * NL + kv0 + tid];
        biasS[tid] = mv ? 0.f : -10000.f;
      }
    }
    __syncthreads();

    // ---- S = Q K^T (two 16-col kv tiles)
    f32x4 s0 = {0.f, 0.f, 0.f, 0.f}, s1 = {0.f, 0.f, 0.f, 0.f};
#pragma unroll
    for (int ch = 0; ch < 8; ++ch) {
      int cbase = ch * 64 + g * 16;
      int b0 = (cc * 512 + cbase) ^ ((cc & 7) << 4);
      int b1 = ((cc + 16) * 512 + cbase) ^ ((cc & 7) << 4);
      short8 k0 = *reinterpret_cast<const short8*>((const char*)Ks + b0);
      short8 k1 = *reinterpret_cast<const short8*>((const char*)Ks + b1);
      s0 = __builtin_amdgcn_mfma_f32_16x16x32_bf16(qf[ch], k0, s0, 0, 0, 0);
      s1 = __builtin_amdgcn_mfma_f32_16x16x32_bf16(qf[ch], k1, s1, 0, 0, 0);
    }
    // ---- biases: padding mask (all rows), causal (diagonal tile and beyond)
    float bi0 = biasS[cc], bi1 = biasS[16 + cc];
    s0 += bi0;
    s1 += bi1;
    if (tix >= qt) {
      int kvg0 = kv0 + cc, kvg1 = kv0 + 16 + cc;
      int qg = qb + 16 * wv + 4 * g;
#pragma unroll
      for (int r = 0; r < 4; ++r) {
        if (kvg0 > qg + r) s0[r] -= 10000.f;
        if (kvg1 > qg + r) s1[r] -= 10000.f;
      }
    }
    // ---- online softmax (q-row 4g+r lives in the 16 lanes sharing g)
    float rmax[4], alpha[4], rsum[4];
#pragma unroll
    for (int r = 0; r < 4; ++r) rmax[r] = fmaxf(s0[r], s1[r]);
#pragma unroll
    for (int off = 8; off >= 1; off >>= 1) {
#pragma unroll
      for (int r = 0; r < 4; ++r) rmax[r] = fmaxf(rmax[r], __shfl_xor(rmax[r], off));
    }
#pragma unroll
    for (int r = 0; r < 4; ++r) {
      float mn = fmaxf(m_run[r], rmax[r]);
      alpha[r] = __expf(m_run[r] - mn);
      m_run[r] = mn;
    }
#pragma unroll
    for (int r = 0; r < 4; ++r) {
      s0[r] = __expf(s0[r] - m_run[r]);
      s1[r] = __expf(s1[r] - m_run[r]);
      rsum[r] = s0[r] + s1[r];
    }
#pragma unroll
    for (int off = 8; off >= 1; off >>= 1) {
#pragma unroll
      for (int r = 0; r < 4; ++r) rsum[r] += __shfl_xor(rsum[r], off);
    }
    f32x4 av = {alpha[0], alpha[1], alpha[2], alpha[3]};
#pragma unroll
    for (int r = 0; r < 4; ++r) l_run[r] = l_run[r] * alpha[r] + rsum[r];
#pragma unroll
    for (int i = 0; i < 16; ++i) acc[i] *= av;

    // ---- P -> LDS (bf16) so PV's A-operand reads contiguous kv
    unsigned short* pw = &Ps[wv][0];
#pragma unroll
    for (int r = 0; r < 4; ++r) {
      pw[(4 * g + r) * KVB + cc] = bf16rne(s0[r]);
      pw[(4 * g + r) * KVB + 16 + cc] = bf16rne(s1[r]);
    }
    asm volatile("s_waitcnt lgkmcnt(0)" ::: "memory");
    short8 pa = *reinterpret_cast<const short8*>((const char*)pw + cc * 64 + g * 16);

    // ---- O += P V, V read via hardware transpose (ds_read_b64_tr_b16)
#pragma unroll
    for (int h8 = 0; h8 < 2; ++h8) {
      short4v lo[8], hi[8];
#pragma unroll
      for (int f8 = 0; f8 < 8; ++f8) {
        const int ft = h8 * 8 + f8;
        asm volatile("ds_read_b64_tr_b16 %0, %1 offset:%2"
                     : "=&v"(lo[f8])
                     : "v"(va), "i"(ft * 128)
                     : "memory");
        asm volatile("ds_read_b64_tr_b16 %0, %1 offset:%2"
                     : "=&v"(hi[f8])
                     : "v"(va), "i"(ft * 128 + 2048)
                     : "memory");
      }
      asm volatile("s_waitcnt lgkmcnt(0)" ::: "memory");
      __builtin_amdgcn_sched_barrier(0);
#pragma unroll
      for (int f8 = 0; f8 < 8; ++f8) {
        short8 vb = __builtin_shufflevector(lo[f8], hi[f8], 0, 1, 2, 3, 4, 5, 6, 7);
        acc[h8 * 8 + f8] =
            __builtin_amdgcn_mfma_f32_16x16x32_bf16(pa, vb, acc[h8 * 8 + f8], 0, 0, 0);
      }
    }
  }

  // ---- epilogue: O /= l, store fp32
  float inv[4];
#pragma unroll
  for (int r = 0; r < 4; ++r) inv[r] = 1.0f / l_run[r];
  float* op = Og + ((size_t)b * NL + (qb + 16 * wv)) * ND;
#pragma unroll
  for (int ft = 0; ft < 16; ++ft) {
#pragma unroll
    for (int r = 0; r < 4; ++r) {
      op[(size_t)(4 * g + r) * ND + ft * 16 + cc] = acc[ft][r] * inv[r];
    }
  }
}

extern "C" void kernel_launch(void* const* d_in, const int* in_sizes, int n_in,
                              void* d_out, int out_size, void* d_ws, size_t ws_size,
                              hipStream_t stream) {
  (void)in_sizes; (void)n_in; (void)out_size;
  const float* Q = (const float*)d_in[0];
  const float* K = (const float*)d_in[1];
  const float* V = (const float*)d_in[2];
  const int* M = (const int*)d_in[3];
  float* O = (float*)d_out;
  int* modeFlag = (ws_size >= sizeof(int)) ? (int*)d_ws : nullptr;
  if (modeFlag) {
    mask_mode_kernel<<<dim3(1), dim3(64), 0, stream>>>((const unsigned*)M, modeFlag);
  }
  attn_fwd<<<dim3(512), dim3(128), 0, stream>>>(Q, K, V, M, O, modeFlag);
}

// Round 5
// 316.444 us; speedup vs baseline: 1.3178x; 1.3178x over previous
//
#include <hip/hip_runtime.h>
#include <stdint.h>

#define NB 8
#define NL 2048
#define ND 256
#define KVB 32
#define NT_ALL (NL / KVB)
#define NSPLIT 4
#define PART_FLOATS (32 * ND + 64)   // 8192 acc + 32 m + 32 l (padded)

typedef __attribute__((ext_vector_type(8))) short short8;
typedef __attribute__((ext_vector_type(4))) short short4v;
typedef __attribute__((ext_vector_type(4))) float f32x4;

__device__ __forceinline__ unsigned short bf16rne(float x) {
  unsigned u = __builtin_bit_cast(unsigned, x);
  u += 0x7FFFu + ((u >> 16) & 1u);
  return (unsigned short)(u >> 16);
}

__device__ __forceinline__ short8 cvt8(float4 a, float4 b, float scale) {
  short8 v;
  v[0] = (short)bf16rne(a.x * scale);
  v[1] = (short)bf16rne(a.y * scale);
  v[2] = (short)bf16rne(a.z * scale);
  v[3] = (short)bf16rne(a.w * scale);
  v[4] = (short)bf16rne(b.x * scale);
  v[5] = (short)bf16rne(b.y * scale);
  v[6] = (short)bf16rne(b.z * scale);
  v[7] = (short)bf16rne(b.w * scale);
  return v;
}

// Pre-pass: detect mask storage. If any of the first 4096 words is not 0/1,
// the mask is byte-packed (numpy bool) -> flag=1; else int32 words -> flag=0.
__global__ void mask_mode_kernel(const unsigned* __restrict__ M, int* __restrict__ flag) {
  bool bad = false;
  for (int i = threadIdx.x; i < 4096; i += 64) {
    unsigned w = M[i];
    if (w > 1u) bad = true;
  }
  unsigned long long b = __ballot(bad);
  if (threadIdx.x == 0) *flag = (b != 0ULL) ? 1 : 0;
}

// Flash attention fwd with split-kv: each block = (b, q-tile of 32 rows,
// kv-chunk c of nt tiles / split). split==1 -> direct output (normalized);
// split==4 -> unnormalized partial (acc, m, l) to workspace, combined later.
__global__ __launch_bounds__(128, 2)
void attn_fwd(const float* __restrict__ Qg, const float* __restrict__ Kg,
              const float* __restrict__ Vg, const int* __restrict__ Mg,
              float* __restrict__ Og, float* __restrict__ wsP,
              const int* __restrict__ modeFlag, int split) {
  __shared__ unsigned short Ks[KVB * ND];      // 16 KB, row-major + XOR swizzle
  __shared__ unsigned short Vs[KVB * ND];      // 16 KB, subtiled [kv/4][f/16][4][16]
  __shared__ float biasS[KVB];                 // padding-mask bias per kv row
  __shared__ unsigned short Ps[2][16 * KVB];   // per-wave P (bf16)
  __shared__ int contS;                        // needy-extension flag

  const int tid = threadIdx.x;
  const int wv = tid >> 6;       // wave 0/1
  const int lane = tid & 63;
  const int g = lane >> 4;       // 4-lane-group id (0..3)
  const int cc = lane & 15;      // column/lane-in-group (0..15)

  const int maskByteMode = modeFlag ? *modeFlag : 0;

  // chunk id + balanced (qt, 63-qt) pairing inside each chunk-plane
  const int c = blockIdx.x >> 9;       // 0..split-1
  const int bid = blockIdx.x & 511;
  const int half = bid >> 8;
  const int ci = bid & 255;
  const int b = ci >> 5;               // batch 0..7
  const int jj = ci & 31;
  const int qt = half ? (63 - jj) : jj;  // q-tile 0..63
  const int qb = qt * 32;

  const int nt = qt + 1;               // causal tiles: 0..qt
  const int n_per = (nt + split - 1) / split;
  const int t0 = c * n_per;
  const int t1 = min(nt, t0 + n_per);
  const int pid = (b * 64 + qt) * NSPLIT + c;
  float* pp = wsP + (size_t)pid * PART_FLOATS;

  if (t0 >= t1) {  // empty chunk: write identity partial
    for (int i = tid; i < 32 * ND; i += 128) pp[i] = 0.f;
    if (tid < 32) { pp[32 * ND + tid] = -3.0e38f; pp[32 * ND + 32 + tid] = 0.f; }
    return;
  }
  // extension allowed only when this chunk covers the whole causal prefix
  const bool extOK = (t0 == 0) && (t1 == nt);

  // ---- Q fragments: lane holds Q[qrow = cc][ch*32 + g*8 .. +7], scaled 1/16
  const float* qp = Qg + ((size_t)b * NL + (qb + 16 * wv + cc)) * ND;
  short8 qf[8];
#pragma unroll
  for (int ch = 0; ch < 8; ++ch) {
    int f = ch * 32 + g * 8;
    float4 a0 = *reinterpret_cast<const float4*>(qp + f);
    float4 a1 = *reinterpret_cast<const float4*>(qp + f + 4);
    qf[ch] = cvt8(a0, a1, 0.0625f);
  }

  f32x4 acc[16];
#pragma unroll
  for (int i = 0; i < 16; ++i) acc[i] = (f32x4){0.f, 0.f, 0.f, 0.f};
  float m_run[4], l_run[4];
#pragma unroll
  for (int r = 0; r < 4; ++r) { m_run[r] = -3.0e38f; l_run[r] = 0.f; }

  // tr-read: 16-lane-group gather; natural addressing = base + 8 bytes/lane.
  const unsigned vsb = (unsigned)(uintptr_t)(&Vs[0]);
  const unsigned va = vsb + g * 4096 + cc * 8;

  for (int tix = t0; tix < NT_ALL; ++tix) {
    if (tix == t1) {
      if (!extOK) break;
      // continue past the causal prefix only if some row is still stuck in
      // the -10000 tier (whole prefix padding-masked): reference semantics
      // make the causally-masked tail (same tier) compete for mass.
      bool needy = (m_run[0] < -5000.f) || (m_run[1] < -5000.f) ||
                   (m_run[2] < -5000.f) || (m_run[3] < -5000.f);
      unsigned long long bal = __ballot(needy);
      if (tid == 0) contS = 0;
      __syncthreads();
      if (lane == 0 && bal != 0ULL) contS = 1;
      __syncthreads();
      if (contS == 0) break;
    }
    const int kv0 = tix * KVB;
    __syncthreads();
    // ---- stage K,V (fp32 -> bf16) + padding bias
    {
      const float* kt = Kg + ((size_t)b * NL + kv0) * ND;
      const float* vt = Vg + ((size_t)b * NL + kv0) * ND;
#pragma unroll
      for (int it = 0; it < 8; ++it) {
        int idx = it * 128 + tid;   // unit = 8 floats; 32 rows x 32 units
        int row = idx >> 5;
        int u = idx & 31;
        int f = u * 8;
        const float4* kp4 = reinterpret_cast<const float4*>(kt + (size_t)row * ND + f);
        float4 k0 = kp4[0], k1 = kp4[1];
        int kb = (row * 512 + f * 2) ^ ((row & 7) << 4);
        *reinterpret_cast<short8*>((char*)Ks + kb) = cvt8(k0, k1, 1.0f);
        const float4* vp4 = reinterpret_cast<const float4*>(vt + (size_t)row * ND + f);
        float4 v0 = vp4[0], v1 = vp4[1];
        int vb = (row >> 2) * 2048 + (u >> 1) * 128 + (row & 3) * 32 + (u & 1) * 16;
        *reinterpret_cast<short8*>((char*)Vs + vb) = cvt8(v0, v1, 1.0f);
      }
      if (tid < KVB) {
        int mv = maskByteMode
                     ? (int)((const unsigned char*)Mg)[(size_t)b * NL + kv0 + tid]
                     : Mg[(size_t)b * NL + kv0 + tid];
        biasS[tid] = mv ? 0.f : -10000.f;
      }
    }
    __syncthreads();

    // ---- S = Q K^T (two 16-col kv tiles)
    f32x4 s0 = {0.f, 0.f, 0.f, 0.f}, s1 = {0.f, 0.f, 0.f, 0.f};
#pragma unroll
    for (int ch = 0; ch < 8; ++ch) {
      int cbase = ch * 64 + g * 16;
      int b0 = (cc * 512 + cbase) ^ ((cc & 7) << 4);
      int b1 = ((cc + 16) * 512 + cbase) ^ ((cc & 7) << 4);
      short8 k0 = *reinterpret_cast<const short8*>((const char*)Ks + b0);
      short8 k1 = *reinterpret_cast<const short8*>((const char*)Ks + b1);
      s0 = __builtin_amdgcn_mfma_f32_16x16x32_bf16(qf[ch], k0, s0, 0, 0, 0);
      s1 = __builtin_amdgcn_mfma_f32_16x16x32_bf16(qf[ch], k1, s1, 0, 0, 0);
    }
    // ---- biases: padding mask (all rows), causal (diagonal tile and beyond)
    float bi0 = biasS[cc], bi1 = biasS[16 + cc];
    s0 += bi0;
    s1 += bi1;
    if (tix >= qt) {
      int kvg0 = kv0 + cc, kvg1 = kv0 + 16 + cc;
      int qg = qb + 16 * wv + 4 * g;
#pragma unroll
      for (int r = 0; r < 4; ++r) {
        if (kvg0 > qg + r) s0[r] -= 10000.f;
        if (kvg1 > qg + r) s1[r] -= 10000.f;
      }
    }
    // ---- online softmax (q-row 4g+r lives in the 16 lanes sharing g)
    float rmax[4], alpha[4], rsum[4];
#pragma unroll
    for (int r = 0; r < 4; ++r) rmax[r] = fmaxf(s0[r], s1[r]);
#pragma unroll
    for (int off = 8; off >= 1; off >>= 1) {
#pragma unroll
      for (int r = 0; r < 4; ++r) rmax[r] = fmaxf(rmax[r], __shfl_xor(rmax[r], off));
    }
#pragma unroll
    for (int r = 0; r < 4; ++r) {
      float mn = fmaxf(m_run[r], rmax[r]);
      alpha[r] = __expf(m_run[r] - mn);
      m_run[r] = mn;
    }
#pragma unroll
    for (int r = 0; r < 4; ++r) {
      s0[r] = __expf(s0[r] - m_run[r]);
      s1[r] = __expf(s1[r] - m_run[r]);
      rsum[r] = s0[r] + s1[r];
    }
#pragma unroll
    for (int off = 8; off >= 1; off >>= 1) {
#pragma unroll
      for (int r = 0; r < 4; ++r) rsum[r] += __shfl_xor(rsum[r], off);
    }
    f32x4 av = {alpha[0], alpha[1], alpha[2], alpha[3]};
#pragma unroll
    for (int r = 0; r < 4; ++r) l_run[r] = l_run[r] * alpha[r] + rsum[r];
#pragma unroll
    for (int i = 0; i < 16; ++i) acc[i] *= av;

    // ---- P -> LDS (bf16) so PV's A-operand reads contiguous kv
    unsigned short* pw = &Ps[wv][0];
#pragma unroll
    for (int r = 0; r < 4; ++r) {
      pw[(4 * g + r) * KVB + cc] = bf16rne(s0[r]);
      pw[(4 * g + r) * KVB + 16 + cc] = bf16rne(s1[r]);
    }
    asm volatile("s_waitcnt lgkmcnt(0)" ::: "memory");
    short8 pa = *reinterpret_cast<const short8*>((const char*)pw + cc * 64 + g * 16);

    // ---- O += P V, V read via hardware transpose (ds_read_b64_tr_b16)
#pragma unroll
    for (int h8 = 0; h8 < 2; ++h8) {
      short4v lo[8], hi[8];
#pragma unroll
      for (int f8 = 0; f8 < 8; ++f8) {
        const int ft = h8 * 8 + f8;
        asm volatile("ds_read_b64_tr_b16 %0, %1 offset:%2"
                     : "=&v"(lo[f8])
                     : "v"(va), "i"(ft * 128)
                     : "memory");
        asm volatile("ds_read_b64_tr_b16 %0, %1 offset:%2"
                     : "=&v"(hi[f8])
                     : "v"(va), "i"(ft * 128 + 2048)
                     : "memory");
      }
      asm volatile("s_waitcnt lgkmcnt(0)" ::: "memory");
      __builtin_amdgcn_sched_barrier(0);
#pragma unroll
      for (int f8 = 0; f8 < 8; ++f8) {
        short8 vb = __builtin_shufflevector(lo[f8], hi[f8], 0, 1, 2, 3, 4, 5, 6, 7);
        acc[h8 * 8 + f8] =
            __builtin_amdgcn_mfma_f32_16x16x32_bf16(pa, vb, acc[h8 * 8 + f8], 0, 0, 0);
      }
    }
  }

  if (split == 1) {
    // ---- epilogue: O /= l, store fp32
    float inv[4];
#pragma unroll
    for (int r = 0; r < 4; ++r) inv[r] = 1.0f / l_run[r];
    float* op = Og + ((size_t)b * NL + (qb + 16 * wv)) * ND;
#pragma unroll
    for (int ft = 0; ft < 16; ++ft) {
#pragma unroll
      for (int r = 0; r < 4; ++r) {
        op[(size_t)(4 * g + r) * ND + ft * 16 + cc] = acc[ft][r] * inv[r];
      }
    }
  } else {
    // ---- partial epilogue: unnormalized acc + (m, l) per row
#pragma unroll
    for (int ft = 0; ft < 16; ++ft) {
#pragma unroll
      for (int r = 0; r < 4; ++r) {
        int rr = 16 * wv + 4 * g + r;
        pp[(size_t)rr * ND + ft * 16 + cc] = acc[ft][r];
      }
    }
    if (cc == 0) {
#pragma unroll
      for (int r = 0; r < 4; ++r) {
        int rr = 16 * wv + 4 * g + r;
        pp[32 * ND + rr] = m_run[r];
        pp[32 * ND + 32 + rr] = l_run[r];
      }
    }
  }
}

// Combine NSPLIT partials per (b, qt): exact log-sum-exp merge.
__global__ __launch_bounds__(128)
void attn_combine(const float* __restrict__ wsP, float* __restrict__ Og) {
  const int bid = blockIdx.x;        // 0..511 = b*64 + qt
  const int b = bid >> 6;
  const int qt = bid & 63;
  const int tid = threadIdx.x;
  const int r = tid >> 2;            // row 0..31
  const int sub = tid & 3;           // column quarter
  const float* p0 = wsP + (size_t)bid * NSPLIT * PART_FLOATS;

  float m[NSPLIT], l[NSPLIT];
#pragma unroll
  for (int cch = 0; cch < NSPLIT; ++cch) {
    m[cch] = p0[(size_t)cch * PART_FLOATS + 32 * ND + r];
    l[cch] = p0[(size_t)cch * PART_FLOATS + 32 * ND + 32 + r];
  }
  float M = m[0];
#pragma unroll
  for (int cch = 1; cch < NSPLIT; ++cch) M = fmaxf(M, m[cch]);
  float s[NSPLIT], L = 0.f;
#pragma unroll
  for (int cch = 0; cch < NSPLIT; ++cch) {
    s[cch] = __expf(m[cch] - M);
    L += l[cch] * s[cch];
  }
  float invL = 1.0f / L;
  const int colb = sub * 64;
  float* op = Og + (((size_t)b * NL + qt * 32 + r) * ND) + colb;
#pragma unroll
  for (int k = 0; k < 16; ++k) {
    float o0 = 0.f, o1 = 0.f, o2 = 0.f, o3 = 0.f;
#pragma unroll
    for (int cch = 0; cch < NSPLIT; ++cch) {
      float4 a = *reinterpret_cast<const float4*>(
          p0 + (size_t)cch * PART_FLOATS + (size_t)r * ND + colb + k * 4);
      o0 += a.x * s[cch];
      o1 += a.y * s[cch];
      o2 += a.z * s[cch];
      o3 += a.w * s[cch];
    }
    float4 o = {o0 * invL, o1 * invL, o2 * invL, o3 * invL};
    *reinterpret_cast<float4*>(op + k * 4) = o;
  }
}

extern "C" void kernel_launch(void* const* d_in, const int* in_sizes, int n_in,
                              void* d_out, int out_size, void* d_ws, size_t ws_size,
                              hipStream_t stream) {
  (void)in_sizes; (void)n_in; (void)out_size;
  const float* Q = (const float*)d_in[0];
  const float* K = (const float*)d_in[1];
  const float* V = (const float*)d_in[2];
  const int* M = (const int*)d_in[3];
  float* O = (float*)d_out;

  int* modeFlag = (ws_size >= sizeof(int)) ? (int*)d_ws : nullptr;
  float* wsP = (float*)((char*)d_ws + 256);
  const size_t need = 256 + (size_t)512 * NSPLIT * PART_FLOATS * sizeof(float);
  const int split = (ws_size >= need) ? NSPLIT : 1;

  if (modeFlag) {
    mask_mode_kernel<<<dim3(1), dim3(64), 0, stream>>>((const unsigned*)M, modeFlag);
  }
  attn_fwd<<<dim3(512 * split), dim3(128), 0, stream>>>(Q, K, V, M, O, wsP, modeFlag,
                                                        split);
  if (split == NSPLIT) {
    attn_combine<<<dim3(512), dim3(128), 0, stream>>>(wsP, O);
  }
}

// Round 6
// 191.574 us; speedup vs baseline: 2.1768x; 1.6518x over previous
//
#include <hip/hip_runtime.h>
#include <stdint.h>

#define NL 2048
#define ND 256
#define KVB 32
#define QB 64
#define NQT 32              // 64-row q-tiles per batch
#define NT_ALL (NL / KVB)   // 64 kv tiles per batch
#define NSPLIT 4
#define TILE_BYTES (KVB * ND * 2)          // 16 KB LDS image per kv tile
#define PART_BYTES (QB * ND * 2 + QB * 8)  // bf16 acc + fp32 m,l = 33280
#define WS_K 256
#define WS_V (WS_K + 8 * NT_ALL * TILE_BYTES)
#define WS_P (WS_V + 8 * NT_ALL * TILE_BYTES)

typedef __attribute__((ext_vector_type(8))) short short8;
typedef __attribute__((ext_vector_type(4))) short short4v;
typedef __attribute__((ext_vector_type(4))) float f32x4;
typedef __attribute__((ext_vector_type(8))) unsigned short ushort8;

__device__ __forceinline__ unsigned short bf16rne(float x) {
  unsigned u = __builtin_bit_cast(unsigned, x);
  u += 0x7FFFu + ((u >> 16) & 1u);
  return (unsigned short)(u >> 16);
}

__device__ __forceinline__ short8 cvt8(float4 a, float4 b, float scale) {
  short8 v;
  v[0] = (short)bf16rne(a.x * scale);
  v[1] = (short)bf16rne(a.y * scale);
  v[2] = (short)bf16rne(a.z * scale);
  v[3] = (short)bf16rne(a.w * scale);
  v[4] = (short)bf16rne(b.x * scale);
  v[5] = (short)bf16rne(b.y * scale);
  v[6] = (short)bf16rne(b.z * scale);
  v[7] = (short)bf16rne(b.w * scale);
  return v;
}

// Mask storage probe: any word not 0/1 in the first 4096 words => byte bools.
__global__ void mask_mode_kernel(const unsigned* __restrict__ M, int* __restrict__ flag) {
  bool bad = false;
  for (int i = threadIdx.x; i < 4096; i += 64) {
    if (M[i] > 1u) bad = true;
  }
  unsigned long long b = __ballot(bad);
  if (threadIdx.x == 0) *flag = (b != 0ULL) ? 1 : 0;
}

// One-shot K,V fp32->bf16 conversion, stored as the EXACT per-tile LDS images
// (K row-major + XOR swizzle; V in tr-read subtile layout), so the main kernel
// stages with linear global_load_lds DMA (no VALU, no ds_write conflicts).
__global__ __launch_bounds__(128)
void convert_kv(const float* __restrict__ K, const float* __restrict__ V,
                unsigned char* __restrict__ ws) {
  const int t = blockIdx.x;  // b*64 + tix
  const int b = t >> 6, tix = t & 63;
  const float* kt = K + ((size_t)b * NL + tix * KVB) * ND;
  const float* vt = V + ((size_t)b * NL + tix * KVB) * ND;
  unsigned char* kd = ws + WS_K + (size_t)t * TILE_BYTES;
  unsigned char* vd = ws + WS_V + (size_t)t * TILE_BYTES;
#pragma unroll
  for (int it = 0; it < 8; ++it) {
    int idx = it * 128 + threadIdx.x;
    int row = idx >> 5, u = idx & 31, f = u * 8;
    const float4* kp = (const float4*)(kt + (size_t)row * ND + f);
    int kb = (row * 512 + f * 2) ^ ((row & 7) << 4);
    *(short8*)(kd + kb) = cvt8(kp[0], kp[1], 1.0f);
    const float4* vp = (const float4*)(vt + (size_t)row * ND + f);
    int vb = (row >> 2) * 2048 + (u >> 1) * 128 + (row & 3) * 32 + (u & 1) * 16;
    *(short8*)(vd + vb) = cvt8(vp[0], vp[1], 1.0f);
  }
}

// Flash attention fwd, split-kv x4, 4 waves/block (64 q-rows), double-buffered
// LDS with global_load_lds DMA prefetch (2-phase pipeline, 1 barrier/tile).
// Causal+padding are -1e4 additive biases exactly like the reference; rows with
// a fully-masked causal prefix extend into kv>q tiles ("needy" path, qt==0).
__global__ __launch_bounds__(256, 2)
void attn_fwd(const float* __restrict__ Qg, const int* __restrict__ Mg,
              unsigned char* ws, const int* __restrict__ modeFlag) {
  __shared__ unsigned short Ks[2][KVB * ND];   // 2 x 16 KB
  __shared__ unsigned short Vs[2][KVB * ND];   // 2 x 16 KB
  __shared__ float biasS[2][KVB];
  __shared__ unsigned short Ps[4][16 * KVB];   // per-wave P (bf16)
  __shared__ int contS;

  const int tid = threadIdx.x;
  const int wv = tid >> 6;      // wave 0..3
  const int lane = tid & 63;
  const int g = lane >> 4;      // 4-lane-group id
  const int cc = lane & 15;     // lane-in-group
  const int maskByteMode = *modeFlag;

  const int c = blockIdx.x >> 8;     // kv-chunk 0..3
  const int bid = blockIdx.x & 255;
  const int b = bid >> 5;            // batch
  const int jj = bid & 31;
  const int qt = (jj & 1) ? (31 - (jj >> 1)) : (jj >> 1);  // long/short interleave
  const int qb = qt * QB;

  const int nt = 2 * qt + 2;         // causal kv tiles: 0..nt-1
  int n_per = (nt + NSPLIT - 1) / NSPLIT;
  int t0 = c * n_per, t1 = min(nt, t0 + n_per);
  // qt==0 must keep its whole prefix in one chunk so the needy extension works.
  if (qt == 0) { t0 = (c == 0) ? 0 : nt; t1 = nt; }
  const int pid = (b * NQT + qt) * NSPLIT + c;
  unsigned char* pp = ws + WS_P + (size_t)pid * PART_BYTES;
  unsigned short* ppA = (unsigned short*)pp;
  float* ppM = (float*)(pp + QB * ND * 2);
  float* ppL = ppM + QB;

  if (t0 >= t1) {  // empty chunk -> identity partial
    for (int i = tid; i < QB * ND; i += 256) ppA[i] = 0;
    if (tid < QB) { ppM[tid] = -3.0e38f; ppL[tid] = 0.f; }
    return;
  }
  const bool extOK = (t0 == 0) && (t1 == nt);

  auto stage_tile = [&](int tix, int bi) {
    const unsigned char* kg = ws + WS_K + ((size_t)(b * NT_ALL + tix)) * TILE_BYTES;
    const unsigned char* vg = ws + WS_V + ((size_t)(b * NT_ALL + tix)) * TILE_BYTES;
#pragma unroll
    for (int s = 0; s < 4; ++s) {
      const int seg = wv * 4 + s;  // wave-uniform LDS dest; per-lane global src
      __builtin_amdgcn_global_load_lds(
          (const __attribute__((address_space(1))) unsigned int*)(kg + seg * 1024 + lane * 16),
          (__attribute__((address_space(3))) unsigned int*)((unsigned char*)&Ks[bi][0] + seg * 1024),
          16, 0, 0);
      __builtin_amdgcn_global_load_lds(
          (const __attribute__((address_space(1))) unsigned int*)(vg + seg * 1024 + lane * 16),
          (__attribute__((address_space(3))) unsigned int*)((unsigned char*)&Vs[bi][0] + seg * 1024),
          16, 0, 0);
    }
    if (tid < KVB) {
      int mv = maskByteMode
                   ? (int)((const unsigned char*)Mg)[(size_t)b * NL + tix * KVB + tid]
                   : Mg[(size_t)b * NL + tix * KVB + tid];
      biasS[bi][tid] = mv ? 0.f : -10000.f;
    }
  };

  // ---- Q fragments: lane holds Q[qb+16wv+cc][ch*32 + g*8 .. +7], scaled 1/16
  const float* qp = Qg + ((size_t)b * NL + (qb + 16 * wv + cc)) * ND;
  short8 qf[8];
#pragma unroll
  for (int ch = 0; ch < 8; ++ch) {
    int f = ch * 32 + g * 8;
    float4 a0 = *reinterpret_cast<const float4*>(qp + f);
    float4 a1 = *reinterpret_cast<const float4*>(qp + f + 4);
    qf[ch] = cvt8(a0, a1, 0.0625f);
  }

  f32x4 acc[16];
#pragma unroll
  for (int i = 0; i < 16; ++i) acc[i] = (f32x4){0.f, 0.f, 0.f, 0.f};
  float m_run[4], l_run[4];
#pragma unroll
  for (int r = 0; r < 4; ++r) { m_run[r] = -3.0e38f; l_run[r] = 0.f; }

  int buf = 0;
  stage_tile(t0, 0);
  __syncthreads();           // drains DMA (vmcnt) + bias writes
  bool staged = true;

  for (int tix = t0; tix < NT_ALL; ++tix) {
    if (tix == t1) {
      if (!extOK) break;
      bool needy = (m_run[0] < -5000.f) || (m_run[1] < -5000.f) ||
                   (m_run[2] < -5000.f) || (m_run[3] < -5000.f);
      unsigned long long bal = __ballot(needy);
      if (tid == 0) contS = 0;
      __syncthreads();
      if (lane == 0 && bal != 0ULL) contS = 1;
      __syncthreads();
      if (contS == 0) break;
    }
    if (!staged) { stage_tile(tix, buf); __syncthreads(); }
    const bool pf = (tix + 1 < t1);
    if (pf) stage_tile(tix + 1, buf ^ 1);  // DMA flies under this tile's compute
    const int kv0 = tix * KVB;

    // ---- S = Q K^T (two 16-col kv tiles)
    const char* ksB = (const char*)&Ks[buf][0];
    f32x4 s0 = {0.f, 0.f, 0.f, 0.f}, s1 = {0.f, 0.f, 0.f, 0.f};
#pragma unroll
    for (int ch = 0; ch < 8; ++ch) {
      int cbase = ch * 64 + g * 16;
      int b0 = (cc * 512 + cbase) ^ ((cc & 7) << 4);
      int b1 = ((cc + 16) * 512 + cbase) ^ ((cc & 7) << 4);
      short8 k0 = *reinterpret_cast<const short8*>(ksB + b0);
      short8 k1 = *reinterpret_cast<const short8*>(ksB + b1);
      s0 = __builtin_amdgcn_mfma_f32_16x16x32_bf16(qf[ch], k0, s0, 0, 0, 0);
      s1 = __builtin_amdgcn_mfma_f32_16x16x32_bf16(qf[ch], k1, s1, 0, 0, 0);
    }
    // ---- biases: padding (all rows), causal (diagonal tiles and beyond)
    float bi0 = biasS[buf][cc], bi1 = biasS[buf][16 + cc];
    s0 += bi0;
    s1 += bi1;
    if (kv0 + KVB - 1 > qb) {
      int kvg0 = kv0 + cc, kvg1 = kv0 + 16 + cc;
      int qg = qb + 16 * wv + 4 * g;
#pragma unroll
      for (int r = 0; r < 4; ++r) {
        if (kvg0 > qg + r) s0[r] -= 10000.f;
        if (kvg1 > qg + r) s1[r] -= 10000.f;
      }
    }
    // ---- online softmax (row 4g+r lives in the 16 lanes sharing g)
    float rmax[4], alpha[4], rsum[4];
#pragma unroll
    for (int r = 0; r < 4; ++r) rmax[r] = fmaxf(s0[r], s1[r]);
#pragma unroll
    for (int off = 8; off >= 1; off >>= 1) {
#pragma unroll
      for (int r = 0; r < 4; ++r) rmax[r] = fmaxf(rmax[r], __shfl_xor(rmax[r], off));
    }
#pragma unroll
    for (int r = 0; r < 4; ++r) {
      float mn = fmaxf(m_run[r], rmax[r]);
      alpha[r] = __expf(m_run[r] - mn);
      m_run[r] = mn;
    }
#pragma unroll
    for (int r = 0; r < 4; ++r) {
      s0[r] = __expf(s0[r] - m_run[r]);
      s1[r] = __expf(s1[r] - m_run[r]);
      rsum[r] = s0[r] + s1[r];
    }
#pragma unroll
    for (int off = 8; off >= 1; off >>= 1) {
#pragma unroll
      for (int r = 0; r < 4; ++r) rsum[r] += __shfl_xor(rsum[r], off);
    }
    f32x4 av = {alpha[0], alpha[1], alpha[2], alpha[3]};
#pragma unroll
    for (int r = 0; r < 4; ++r) l_run[r] = l_run[r] * alpha[r] + rsum[r];
#pragma unroll
    for (int i = 0; i < 16; ++i) acc[i] *= av;

    // ---- P -> per-wave LDS so PV's A-operand reads contiguous kv
    unsigned short* pw = &Ps[wv][0];
#pragma unroll
    for (int r = 0; r < 4; ++r) {
      pw[(4 * g + r) * KVB + cc] = bf16rne(s0[r]);
      pw[(4 * g + r) * KVB + 16 + cc] = bf16rne(s1[r]);
    }
    asm volatile("s_waitcnt lgkmcnt(0)" ::: "memory");
    short8 pa = *reinterpret_cast<const short8*>((const char*)pw + cc * 64 + g * 16);

    // ---- O += P V via hardware transpose reads (8 B/lane natural addressing)
    const unsigned va = (unsigned)(uintptr_t)&Vs[buf][0] + g * 4096 + cc * 8;
#pragma unroll
    for (int h8 = 0; h8 < 2; ++h8) {
      short4v lo[8], hi[8];
#pragma unroll
      for (int f8 = 0; f8 < 8; ++f8) {
        const int ft = h8 * 8 + f8;
        asm volatile("ds_read_b64_tr_b16 %0, %1 offset:%2"
                     : "=&v"(lo[f8]) : "v"(va), "i"(ft * 128) : "memory");
        asm volatile("ds_read_b64_tr_b16 %0, %1 offset:%2"
                     : "=&v"(hi[f8]) : "v"(va), "i"(ft * 128 + 2048) : "memory");
      }
      asm volatile("s_waitcnt lgkmcnt(0)" ::: "memory");
      __builtin_amdgcn_sched_barrier(0);
#pragma unroll
      for (int f8 = 0; f8 < 8; ++f8) {
        short8 vb = __builtin_shufflevector(lo[f8], hi[f8], 0, 1, 2, 3, 4, 5, 6, 7);
        acc[h8 * 8 + f8] =
            __builtin_amdgcn_mfma_f32_16x16x32_bf16(pa, vb, acc[h8 * 8 + f8], 0, 0, 0);
      }
    }

    __syncthreads();  // drains prefetch DMA + releases buf for next stage
    buf ^= 1;
    staged = pf;
  }

  // ---- partial epilogue: bf16 unnormalized acc + fp32 (m, l)
#pragma unroll
  for (int ft = 0; ft < 16; ++ft) {
#pragma unroll
    for (int r = 0; r < 4; ++r) {
      int rr = 16 * wv + 4 * g + r;
      ppA[rr * ND + ft * 16 + cc] = bf16rne(acc[ft][r]);
    }
  }
  if (cc == 0) {
#pragma unroll
    for (int r = 0; r < 4; ++r) {
      int rr = 16 * wv + 4 * g + r;
      ppM[rr] = m_run[r];
      ppL[rr] = l_run[r];
    }
  }
}

// Exact log-sum-exp merge of NSPLIT partials per (b, q-tile).
__global__ __launch_bounds__(256)
void attn_combine(const unsigned char* __restrict__ ws, float* __restrict__ Og) {
  const int bid = blockIdx.x;  // b*32 + qt
  const int b = bid >> 5, qt = bid & 31;
  const int tid = threadIdx.x;
  const int r = tid >> 2, sub = tid & 3;
  const unsigned char* p0 = ws + WS_P + (size_t)bid * NSPLIT * PART_BYTES;

  float m[NSPLIT], l[NSPLIT];
#pragma unroll
  for (int cch = 0; cch < NSPLIT; ++cch) {
    const unsigned char* pc = p0 + (size_t)cch * PART_BYTES;
    m[cch] = *(const float*)(pc + QB * ND * 2 + r * 4);
    l[cch] = *(const float*)(pc + QB * ND * 2 + QB * 4 + r * 4);
  }
  float M = fmaxf(fmaxf(m[0], m[1]), fmaxf(m[2], m[3]));
  float s[NSPLIT], L = 0.f;
#pragma unroll
  for (int cch = 0; cch < NSPLIT; ++cch) {
    s[cch] = __expf(m[cch] - M);
    L += l[cch] * s[cch];
  }
  const float invL = 1.0f / L;
  float* op = Og + ((size_t)(b * NL) + qt * QB + r) * ND + sub * 64;
#pragma unroll
  for (int k = 0; k < 8; ++k) {
    float o[8];
#pragma unroll
    for (int j = 0; j < 8; ++j) o[j] = 0.f;
#pragma unroll
    for (int cch = 0; cch < NSPLIT; ++cch) {
      ushort8 a = *(const ushort8*)(p0 + (size_t)cch * PART_BYTES +
                                    ((size_t)r * ND + sub * 64 + k * 8) * 2);
#pragma unroll
      for (int j = 0; j < 8; ++j) {
        unsigned u = ((unsigned)a[j]) << 16;
        o[j] += __builtin_bit_cast(float, u) * s[cch];
      }
    }
    float4 o0 = {o[0] * invL, o[1] * invL, o[2] * invL, o[3] * invL};
    float4 o1 = {o[4] * invL, o[5] * invL, o[6] * invL, o[7] * invL};
    *(float4*)(op + k * 8) = o0;
    *(float4*)(op + k * 8 + 4) = o1;
  }
}

extern "C" void kernel_launch(void* const* d_in, const int* in_sizes, int n_in,
                              void* d_out, int out_size, void* d_ws, size_t ws_size,
                              hipStream_t stream) {
  (void)in_sizes; (void)n_in; (void)out_size; (void)ws_size;  // ws >= 67.7MB proven in r5
  const float* Q = (const float*)d_in[0];
  const float* K = (const float*)d_in[1];
  const float* V = (const float*)d_in[2];
  const int* M = (const int*)d_in[3];
  unsigned char* ws = (unsigned char*)d_ws;

  mask_mode_kernel<<<dim3(1), dim3(64), 0, stream>>>((const unsigned*)M, (int*)ws);
  convert_kv<<<dim3(512), dim3(128), 0, stream>>>(K, V, ws);
  attn_fwd<<<dim3(256 * NSPLIT), dim3(256), 0, stream>>>(Q, M, ws, (const int*)ws);
  attn_combine<<<dim3(256), dim3(256), 0, stream>>>(ws, (float*)d_out);
}

// Round 7
// 118.225 us; speedup vs baseline: 3.5274x; 1.6204x over previous
//
#include <hip/hip_runtime.h>
#include <stdint.h>

#define NL 2048
#define ND 256
#define KVB 32
#define QB 64
#define NQT 32                      // 64-row q-tiles per batch
#define NT_ALL (NL / KVB)           // 64 kv tiles per batch
#define CHUNK 8                     // kv tiles per block (balanced schedule)
#define NCHUNKS_B 151               // 8 (qt=0 full range) + sum_{qt=1..31}(qt/4+1)
#define TILE_BYTES (KVB * ND * 2)   // 16 KB LDS image per kv tile
#define IMG (8 * NT_ALL * TILE_BYTES)
#define WS_K 256
#define WS_V (WS_K + IMG)
#define WS_Q (WS_V + IMG)
#define WS_P (WS_Q + IMG)
#define PART_BYTES (QB * ND * 2 + QB * 8)  // bf16 acc + fp32 m,l = 33280

typedef __attribute__((ext_vector_type(8))) short short8;
typedef __attribute__((ext_vector_type(4))) short short4v;
typedef __attribute__((ext_vector_type(4))) float f32x4;
typedef __attribute__((ext_vector_type(8))) unsigned short ushort8;

__device__ __forceinline__ unsigned short bf16rne(float x) {
  unsigned u = __builtin_bit_cast(unsigned, x);
  u += 0x7FFFu + ((u >> 16) & 1u);
  return (unsigned short)(u >> 16);
}

__device__ __forceinline__ short8 cvt8(float4 a, float4 b, float scale) {
  short8 v;
  v[0] = (short)bf16rne(a.x * scale);
  v[1] = (short)bf16rne(a.y * scale);
  v[2] = (short)bf16rne(a.z * scale);
  v[3] = (short)bf16rne(a.w * scale);
  v[4] = (short)bf16rne(b.x * scale);
  v[5] = (short)bf16rne(b.y * scale);
  v[6] = (short)bf16rne(b.z * scale);
  v[7] = (short)bf16rne(b.w * scale);
  return v;
}

// Mask storage probe: any word not 0/1 in the first 4096 words => byte bools.
__global__ void mask_mode_kernel(const unsigned* __restrict__ M, int* __restrict__ flag) {
  bool bad = false;
  for (int i = threadIdx.x; i < 4096; i += 64) {
    if (M[i] > 1u) bad = true;
  }
  unsigned long long b = __ballot(bad);
  if (threadIdx.x == 0) *flag = (b != 0ULL) ? 1 : 0;
}

// One-shot Q,K,V fp32->bf16 conversion. K stored as XOR-swizzled LDS tile
// images, V in the tr-read subtile layout, Q row-major with 1/16 pre-applied,
// so the main kernel stages pure linear global_load_lds DMA.
__global__ __launch_bounds__(128)
void convert_qkv(const float* __restrict__ Q, const float* __restrict__ K,
                 const float* __restrict__ V, unsigned char* __restrict__ ws) {
  const int t = blockIdx.x;  // b*64 + tix  (32-row groups)
  const int b = t >> 6, tix = t & 63;
  const float* qt = Q + ((size_t)b * NL + tix * KVB) * ND;
  const float* kt = K + ((size_t)b * NL + tix * KVB) * ND;
  const float* vt = V + ((size_t)b * NL + tix * KVB) * ND;
  unsigned char* qd = ws + WS_Q + (size_t)t * TILE_BYTES;
  unsigned char* kd = ws + WS_K + (size_t)t * TILE_BYTES;
  unsigned char* vd = ws + WS_V + (size_t)t * TILE_BYTES;
#pragma unroll
  for (int it = 0; it < 8; ++it) {
    int idx = it * 128 + threadIdx.x;
    int row = idx >> 5, u = idx & 31, f = u * 8;
    const float4* qp = (const float4*)(qt + (size_t)row * ND + f);
    *(short8*)(qd + (row * 512 + f * 2)) = cvt8(qp[0], qp[1], 0.0625f);
    const float4* kp = (const float4*)(kt + (size_t)row * ND + f);
    int kb = (row * 512 + f * 2) ^ ((row & 7) << 4);
    *(short8*)(kd + kb) = cvt8(kp[0], kp[1], 1.0f);
    const float4* vp = (const float4*)(vt + (size_t)row * ND + f);
    int vb = (row >> 2) * 2048 + (u >> 1) * 128 + (row & 3) * 32 + (u & 1) * 16;
    *(short8*)(vd + vb) = cvt8(vp[0], vp[1], 1.0f);
  }
}

// Flash attention fwd: balanced flat schedule, every block = (b, qt, chunk of
// <=8 kv tiles). qt=0 is scheduled across ALL 64 kv tiles (causal -1e4 applied
// per element), so the LSE combine reproduces the reference's -10000-tier tie
// semantics exactly -- no needy-extension straggler. 4 waves, double-buffered
// global_load_lds DMA, 1 barrier/tile.
__global__ __launch_bounds__(256, 2)
void attn_fwd(const int* __restrict__ Mg, unsigned char* ws,
              const int* __restrict__ modeFlag) {
  __shared__ unsigned short Ks[2][KVB * ND];   // 2 x 16 KB (reused as epilogue scratch)
  __shared__ unsigned short Vs[2][KVB * ND];   // 2 x 16 KB
  __shared__ float biasS[2][KVB];
  __shared__ unsigned short Ps[4][16 * KVB];   // per-wave P (bf16)

  const int tid = threadIdx.x;
  const int wv = tid >> 6;      // wave 0..3
  const int lane = tid & 63;
  const int g = lane >> 4;      // 4-lane-group id
  const int cc = lane & 15;     // lane-in-group
  const int maskByteMode = *modeFlag;

  // ---- flat schedule decode: fid -> (b, qt, c), partial id
  const int fid = blockIdx.x;
  const int b = fid / NCHUNKS_B;
  int rem = fid - b * NCHUNKS_B;
  int qt = 0, c = 0, pbase = 0;
  if (rem < 8) {
    qt = 0; c = rem; pbase = 0;
  } else {
    rem -= 8; pbase = 8;
    for (qt = 1; qt < NQT; ++qt) {
      int n = (qt >> 2) + 1;
      if (rem < n) { c = rem; break; }
      rem -= n; pbase += n;
    }
  }
  const int qb = qt * QB;
  const int nt_s = (qt == 0) ? NT_ALL : (2 * qt + 2);
  const int t0 = c * CHUNK;
  const int t1 = min(nt_s, t0 + CHUNK);
  unsigned char* pp = ws + WS_P + (size_t)(b * NCHUNKS_B + pbase + c) * PART_BYTES;
  unsigned short* ppA = (unsigned short*)pp;
  float* ppM = (float*)(pp + QB * ND * 2);
  float* ppL = ppM + QB;

  auto stage_tile = [&](int tix, int bi) {
    const unsigned char* kg = ws + WS_K + ((size_t)(b * NT_ALL + tix)) * TILE_BYTES;
    const unsigned char* vg = ws + WS_V + ((size_t)(b * NT_ALL + tix)) * TILE_BYTES;
#pragma unroll
    for (int s = 0; s < 4; ++s) {
      const int seg = wv * 4 + s;  // wave-uniform LDS dest; per-lane global src
      __builtin_amdgcn_global_load_lds(
          (const __attribute__((address_space(1))) unsigned int*)(kg + seg * 1024 + lane * 16),
          (__attribute__((address_space(3))) unsigned int*)((unsigned char*)&Ks[bi][0] + seg * 1024),
          16, 0, 0);
      __builtin_amdgcn_global_load_lds(
          (const __attribute__((address_space(1))) unsigned int*)(vg + seg * 1024 + lane * 16),
          (__attribute__((address_space(3))) unsigned int*)((unsigned char*)&Vs[bi][0] + seg * 1024),
          16, 0, 0);
    }
    if (tid < KVB) {
      int mv = maskByteMode
                   ? (int)((const unsigned char*)Mg)[(size_t)b * NL + tix * KVB + tid]
                   : Mg[(size_t)b * NL + tix * KVB + tid];
      biasS[bi][tid] = mv ? 0.f : -10000.f;
    }
  };

  // ---- Q fragments from bf16 image (1/16 pre-applied): row qb+16wv+cc
  const unsigned char* qrow = ws + WS_Q + ((size_t)b * NL + (qb + 16 * wv + cc)) * 512;
  short8 qf[8];
#pragma unroll
  for (int ch = 0; ch < 8; ++ch) {
    qf[ch] = *(const short8*)(qrow + ch * 64 + g * 16);
  }

  f32x4 acc[16];
#pragma unroll
  for (int i = 0; i < 16; ++i) acc[i] = (f32x4){0.f, 0.f, 0.f, 0.f};
  float m_run[4], l_run[4];
#pragma unroll
  for (int r = 0; r < 4; ++r) { m_run[r] = -3.0e38f; l_run[r] = 0.f; }

  int buf = 0;
  stage_tile(t0, 0);
  __syncthreads();  // drains DMA + bias writes

  for (int tix = t0; tix < t1; ++tix) {
    if (tix + 1 < t1) stage_tile(tix + 1, buf ^ 1);  // DMA under this compute
    const int kv0 = tix * KVB;

    // ---- S = Q K^T (two 16-col kv tiles)
    const char* ksB = (const char*)&Ks[buf][0];
    f32x4 s0 = {0.f, 0.f, 0.f, 0.f}, s1 = {0.f, 0.f, 0.f, 0.f};
#pragma unroll
    for (int ch = 0; ch < 8; ++ch) {
      int cbase = ch * 64 + g * 16;
      int b0 = (cc * 512 + cbase) ^ ((cc & 7) << 4);
      int b1 = ((cc + 16) * 512 + cbase) ^ ((cc & 7) << 4);
      short8 k0 = *reinterpret_cast<const short8*>(ksB + b0);
      short8 k1 = *reinterpret_cast<const short8*>(ksB + b1);
      s0 = __builtin_amdgcn_mfma_f32_16x16x32_bf16(qf[ch], k0, s0, 0, 0, 0);
      s1 = __builtin_amdgcn_mfma_f32_16x16x32_bf16(qf[ch], k1, s1, 0, 0, 0);
    }
    // ---- biases: padding (all rows), causal (diagonal tiles and beyond)
    float bi0 = biasS[buf][cc], bi1 = biasS[buf][16 + cc];
    s0 += bi0;
    s1 += bi1;
    if (kv0 + KVB - 1 > qb) {
      int kvg0 = kv0 + cc, kvg1 = kv0 + 16 + cc;
      int qg = qb + 16 * wv + 4 * g;
#pragma unroll
      for (int r = 0; r < 4; ++r) {
        if (kvg0 > qg + r) s0[r] -= 10000.f;
        if (kvg1 > qg + r) s1[r] -= 10000.f;
      }
    }
    // ---- online softmax (row 4g+r lives in the 16 lanes sharing g)
    float rmax[4], alpha[4], rsum[4];
#pragma unroll
    for (int r = 0; r < 4; ++r) rmax[r] = fmaxf(s0[r], s1[r]);
#pragma unroll
    for (int off = 8; off >= 1; off >>= 1) {
#pragma unroll
      for (int r = 0; r < 4; ++r) rmax[r] = fmaxf(rmax[r], __shfl_xor(rmax[r], off));
    }
#pragma unroll
    for (int r = 0; r < 4; ++r) {
      float mn = fmaxf(m_run[r], rmax[r]);
      alpha[r] = __expf(m_run[r] - mn);
      m_run[r] = mn;
    }
#pragma unroll
    for (int r = 0; r < 4; ++r) {
      s0[r] = __expf(s0[r] - m_run[r]);
      s1[r] = __expf(s1[r] - m_run[r]);
      rsum[r] = s0[r] + s1[r];
    }
#pragma unroll
    for (int off = 8; off >= 1; off >>= 1) {
#pragma unroll
      for (int r = 0; r < 4; ++r) rsum[r] += __shfl_xor(rsum[r], off);
    }
    f32x4 av = {alpha[0], alpha[1], alpha[2], alpha[3]};
#pragma unroll
    for (int r = 0; r < 4; ++r) l_run[r] = l_run[r] * alpha[r] + rsum[r];
#pragma unroll
    for (int i = 0; i < 16; ++i) acc[i] *= av;

    // ---- P -> per-wave LDS so PV's A-operand reads contiguous kv
    unsigned short* pw = &Ps[wv][0];
#pragma unroll
    for (int r = 0; r < 4; ++r) {
      pw[(4 * g + r) * KVB + cc] = bf16rne(s0[r]);
      pw[(4 * g + r) * KVB + 16 + cc] = bf16rne(s1[r]);
    }
    asm volatile("s_waitcnt lgkmcnt(0)" ::: "memory");
    short8 pa = *reinterpret_cast<const short8*>((const char*)pw + cc * 64 + g * 16);

    // ---- O += P V via hardware transpose reads (8 B/lane natural addressing)
    const unsigned va = (unsigned)(uintptr_t)&Vs[buf][0] + g * 4096 + cc * 8;
#pragma unroll
    for (int h8 = 0; h8 < 2; ++h8) {
      short4v lo[8], hi[8];
#pragma unroll
      for (int f8 = 0; f8 < 8; ++f8) {
        const int ft = h8 * 8 + f8;
        asm volatile("ds_read_b64_tr_b16 %0, %1 offset:%2"
                     : "=&v"(lo[f8]) : "v"(va), "i"(ft * 128) : "memory");
        asm volatile("ds_read_b64_tr_b16 %0, %1 offset:%2"
                     : "=&v"(hi[f8]) : "v"(va), "i"(ft * 128 + 2048) : "memory");
      }
      asm volatile("s_waitcnt lgkmcnt(0)" ::: "memory");
      __builtin_amdgcn_sched_barrier(0);
#pragma unroll
      for (int f8 = 0; f8 < 8; ++f8) {
        short8 vb = __builtin_shufflevector(lo[f8], hi[f8], 0, 1, 2, 3, 4, 5, 6, 7);
        acc[h8 * 8 + f8] =
            __builtin_amdgcn_mfma_f32_16x16x32_bf16(pa, vb, acc[h8 * 8 + f8], 0, 0, 0);
      }
    }

    __syncthreads();  // drains prefetch DMA + releases buf
    buf ^= 1;
  }

  // ---- epilogue: transpose acc through LDS (reuse Ks, 32 KB), store 16B-wide
  unsigned short* sc = (unsigned short*)&Ks[0][0];
#pragma unroll
  for (int ft = 0; ft < 16; ++ft) {
#pragma unroll
    for (int r = 0; r < 4; ++r) {
      sc[(16 * wv + 4 * g + r) * 256 + ft * 16 + cc] = bf16rne(acc[ft][r]);
    }
  }
  if (cc == 0) {
#pragma unroll
    for (int r = 0; r < 4; ++r) {
      int rr = 16 * wv + 4 * g + r;
      ppM[rr] = m_run[r];
      ppL[rr] = l_run[r];
    }
  }
  __syncthreads();
  {
    const int row = tid >> 2, q4 = tid & 3;
    const unsigned short* srow = sc + row * 256 + q4 * 64;
#pragma unroll
    for (int k = 0; k < 8; ++k) {
      *(ushort8*)(ppA + (size_t)row * ND + q4 * 64 + k * 8) =
          *(const ushort8*)(srow + k * 8);
    }
  }
}

// Exact log-sum-exp merge of the variable-count partials per (b, q-tile).
__global__ __launch_bounds__(256)
void attn_combine(const unsigned char* __restrict__ ws, float* __restrict__ Og) {
  const int bid = blockIdx.x;  // b*32 + qt
  const int b = bid >> 5, qt = bid & 31;
  const int tid = threadIdx.x;
  const int row = tid >> 2, sub = tid & 3;

  int pbase = 0, nc = 8;
  if (qt > 0) {
    pbase = 8;
    for (int j = 1; j < qt; ++j) pbase += (j >> 2) + 1;
    nc = (qt >> 2) + 1;
  }
  const unsigned char* p0 = ws + WS_P + (size_t)(b * NCHUNKS_B + pbase) * PART_BYTES;

  float M = -3.0e38f;
  for (int c = 0; c < nc; ++c) {
    M = fmaxf(M, *(const float*)(p0 + (size_t)c * PART_BYTES + QB * ND * 2 + row * 4));
  }
  float L = 0.f;
  float o[64];
#pragma unroll
  for (int j = 0; j < 64; ++j) o[j] = 0.f;
  for (int c = 0; c < nc; ++c) {
    const unsigned char* pc = p0 + (size_t)c * PART_BYTES;
    float mm = *(const float*)(pc + QB * ND * 2 + row * 4);
    float ll = *(const float*)(pc + QB * ND * 2 + QB * 4 + row * 4);
    float s = __expf(mm - M);
    L += ll * s;
    const unsigned short* pa =
        (const unsigned short*)pc + (size_t)row * ND + sub * 64;
#pragma unroll
    for (int k = 0; k < 8; ++k) {
      ushort8 a = *(const ushort8*)(pa + k * 8);
#pragma unroll
      for (int j = 0; j < 8; ++j) {
        unsigned u = ((unsigned)a[j]) << 16;
        o[k * 8 + j] += __builtin_bit_cast(float, u) * s;
      }
    }
  }
  const float invL = 1.0f / L;
  float* op = Og + ((size_t)b * NL + qt * QB + row) * ND + sub * 64;
#pragma unroll
  for (int k = 0; k < 16; ++k) {
    float4 v = {o[k * 4] * invL, o[k * 4 + 1] * invL, o[k * 4 + 2] * invL,
                o[k * 4 + 3] * invL};
    *(float4*)(op + k * 4) = v;
  }
}

extern "C" void kernel_launch(void* const* d_in, const int* in_sizes, int n_in,
                              void* d_out, int out_size, void* d_ws, size_t ws_size,
                              hipStream_t stream) {
  (void)in_sizes; (void)n_in; (void)out_size; (void)ws_size;  // ws >= 67.7MB proven (r5)
  const float* Q = (const float*)d_in[0];
  const float* K = (const float*)d_in[1];
  const float* V = (const float*)d_in[2];
  const int* M = (const int*)d_in[3];
  unsigned char* ws = (unsigned char*)d_ws;

  mask_mode_kernel<<<dim3(1), dim3(64), 0, stream>>>((const unsigned*)M, (int*)ws);
  convert_qkv<<<dim3(512), dim3(128), 0, stream>>>(Q, K, V, ws);
  attn_fwd<<<dim3(8 * NCHUNKS_B), dim3(256), 0, stream>>>(M, ws, (const int*)ws);
  attn_combine<<<dim3(256), dim3(256), 0, stream>>>(ws, (float*)d_out);
}